// Round 8
// baseline (6445.257 us; speedup 1.0000x reference)
//
#include <hip/hip_runtime.h>
#include <hip/hip_fp16.h>

// Bidirectional 2-layer LSTM: B=32, T=1024, IN=256, H=256.
// ws layout: xg  f16 [2][32][1024][1024]              = 134,217,728 B
//            hbt u64 [2][8][2 parity][4 b][256 j]     =     262,144 B (tagged h)
// total = 134,479,872 B
//
// Tag protocol (per layer, base B): producer at step st stores (B+st+1, h) into
// parity st&1; consumer at step st polls parity (st+1)&1 for tag B+st.
// L0 base=1, L1 base=4096; hbt memset to 0 each launch (replay-safe).
//
// recur7: rounds 5-7 showed the allocator pins VGPR budget at 85 (6 waves/EU)
// and spills any larger array (FETCH 160MB vs 70MB algorithmic). So: shrink W
// to 32 VGPRs (64 weights as packed half2) and use v_dot2_f32_f16 (f32 acc).
// Thread = (col 0..63, k-quarter); wg = (dir, group of 4 batches, 16-col slice).

#define T_LEN 1024
#define BATCH 32
#define HID   256
#define G4    1024

struct __align__(8) Half4 { __half x, y, z, w; };

typedef _Float16 f16x2 __attribute__((ext_vector_type(2)));

__device__ __forceinline__ f16x2 pack_f16x2(float lo, float hi) {
    f16x2 r; r.x = (_Float16)lo; r.y = (_Float16)hi; return r;
}
__device__ __forceinline__ float dot2acc(f16x2 a, f16x2 b, float c) {
#if __has_builtin(__builtin_amdgcn_fdot2)
    return __builtin_amdgcn_fdot2(a, b, c, false);
#else
    return c + (float)a.x * (float)b.x + (float)a.y * (float)b.y;
#endif
}

__device__ __forceinline__ float sigm(float x) { return 1.0f / (1.0f + __expf(-x)); }
__device__ __forceinline__ float tanh_fast(float x) {
    float e = __expf(2.f * x);            // inf-safe
    return 1.f - 2.f / (e + 1.f);
}

// ---- projection: xg[dir][m][n] = sum_k A[m][k]*W[n][k] + bih[n] + bhh[n], stored f16 ----
__global__ __launch_bounds__(256) void proj_kernel(
    const float* __restrict__ A, int K,
    const float* __restrict__ Wf, const float* __restrict__ Wr,
    const float* __restrict__ bih_f, const float* __restrict__ bhh_f,
    const float* __restrict__ bih_r, const float* __restrict__ bhh_r,
    __half* __restrict__ xg)
{
    const int dir = blockIdx.z;
    const float* __restrict__ W   = dir ? Wr    : Wf;
    const float* __restrict__ bih = dir ? bih_r : bih_f;
    const float* __restrict__ bhh = dir ? bhh_r : bhh_f;
    __half* __restrict__ outp = xg + (size_t)dir * ((size_t)BATCH * T_LEN * G4);

    __shared__ float As[32][132];
    __shared__ float Bs[32][132];

    const int tid = threadIdx.x;
    const int tx  = tid & 15;
    const int ty  = tid >> 4;
    const int tx4 = tx * 4;
    const int ty4 = ty * 4;
    const int m0  = blockIdx.y * 128;
    const int n0  = blockIdx.x * 128;

    float acc[8][8];
    #pragma unroll
    for (int i = 0; i < 8; ++i)
        #pragma unroll
        for (int j = 0; j < 8; ++j) acc[i][j] = 0.f;

    for (int k0 = 0; k0 < K; k0 += 32) {
        #pragma unroll
        for (int it = 0; it < 4; ++it) {
            int f   = tid + it * 256;
            int row = f >> 3;
            int c4  = (f & 7) * 4;
            float4 av = *reinterpret_cast<const float4*>(&A[(size_t)(m0 + row) * K + k0 + c4]);
            float4 bv = *reinterpret_cast<const float4*>(&W[(size_t)(n0 + row) * K + k0 + c4]);
            As[c4 + 0][row] = av.x; As[c4 + 1][row] = av.y;
            As[c4 + 2][row] = av.z; As[c4 + 3][row] = av.w;
            Bs[c4 + 0][row] = bv.x; Bs[c4 + 1][row] = bv.y;
            Bs[c4 + 2][row] = bv.z; Bs[c4 + 3][row] = bv.w;
        }
        __syncthreads();
        #pragma unroll
        for (int k = 0; k < 32; ++k) {
            float4 a0 = *reinterpret_cast<const float4*>(&As[k][ty4]);
            float4 a1 = *reinterpret_cast<const float4*>(&As[k][64 + ty4]);
            float4 b0 = *reinterpret_cast<const float4*>(&Bs[k][tx4]);
            float4 b1 = *reinterpret_cast<const float4*>(&Bs[k][64 + tx4]);
            float a[8] = {a0.x,a0.y,a0.z,a0.w,a1.x,a1.y,a1.z,a1.w};
            float b[8] = {b0.x,b0.y,b0.z,b0.w,b1.x,b1.y,b1.z,b1.w};
            #pragma unroll
            for (int i = 0; i < 8; ++i)
                #pragma unroll
                for (int j = 0; j < 8; ++j)
                    acc[i][j] = fmaf(a[i], b[j], acc[i][j]);
        }
        __syncthreads();
    }

    float bb[8];
    #pragma unroll
    for (int j = 0; j < 8; ++j) {
        int n = n0 + ((j < 4) ? (tx4 + j) : (64 + tx4 + (j - 4)));
        bb[j] = bih[n] + bhh[n];
    }
    #pragma unroll
    for (int i = 0; i < 8; ++i) {
        int m = m0 + ((i < 4) ? (ty4 + i) : (64 + ty4 + (i - 4)));
        Half4 v0, v1;
        v0.x = __float2half(acc[i][0] + bb[0]);
        v0.y = __float2half(acc[i][1] + bb[1]);
        v0.z = __float2half(acc[i][2] + bb[2]);
        v0.w = __float2half(acc[i][3] + bb[3]);
        v1.x = __float2half(acc[i][4] + bb[4]);
        v1.y = __float2half(acc[i][5] + bb[5]);
        v1.z = __float2half(acc[i][6] + bb[6]);
        v1.w = __float2half(acc[i][7] + bb[7]);
        *reinterpret_cast<Half4*>(&outp[(size_t)m * G4 + n0 + tx4])      = v0;
        *reinterpret_cast<Half4*>(&outp[(size_t)m * G4 + n0 + 64 + tx4]) = v1;
    }
}

// ---- cooperative recurrence: fp16 W in 32 VGPRs, fdot2, tagged h exchange ----
// bid = a*64 + m*8 + x. gid = (a&1)*8 + x : d = gid>>3, g = gid&7.
// s = m + (a>>1)*8 (0..15). All 16 slices of (d,g) share bid%8 (same-XCD heuristic).
// thread: col = tid&63 (q=col>>4 gate, jl=col&15), kq = tid>>6 (k-quarter, wave-uniform).
// wg output: h for 4 batches (g*4..g*4+3) x 16 j (s*16..s*16+15).
extern "C" __global__ __launch_bounds__(256, 2) void recur7_kernel(
    const __half* __restrict__ xg,
    const float* __restrict__ Whh_f,           // [1024][256]
    const float* __restrict__ Whh_r,
    float* __restrict__ outp,                  // [32][1024][512]
    unsigned long long* __restrict__ hbt,      // [2][8][2][4][256] tagged
    unsigned int tagbase)
{
    __shared__ f16x2 hl2[4 * 128];   // staged h as half2: [b][128]
    __shared__ float scr[4 * 256];   // partials [kq][b][64 col]

    const int tid = threadIdx.x;
    const int bid = blockIdx.x;
    const int x = bid & 7, m = (bid >> 3) & 7, a = bid >> 6;
    const int gid = (a & 1) * 8 + x;
    const int d = gid >> 3;
    const int g = gid & 7;
    const int s = m + ((a >> 1) << 3);
    const float* __restrict__ Whh = d ? Whh_r : Whh_f;

    const int col  = tid & 63;
    const int kq   = tid >> 6;                    // k-quarter, wave-uniform
    const int q    = col >> 4;
    const int jl   = col & 15;
    const int n_my = (q << 8) + s * 16 + jl;      // gate row in W_hh

    // --- one-time: 64 weights (this row, this k-quarter) as 32 packed half2 ---
    unsigned wh[32];
    {
        const float* wrow = Whh + (size_t)n_my * HID + kq * 64;
        #pragma unroll
        for (int i = 0; i < 16; ++i) {
            float4 wv4 = *reinterpret_cast<const float4*>(&wrow[i * 4]);
            wh[2 * i]     = __builtin_bit_cast(unsigned, pack_f16x2(wv4.x, wv4.y));
            wh[2 * i + 1] = __builtin_bit_cast(unsigned, pack_f16x2(wv4.z, wv4.w));
        }
    }
    #pragma unroll
    for (int i = 0; i < 32; ++i) asm volatile("" : "+v"(wh[i]));   // no remat

    unsigned long long* hb = hbt + (size_t)(d * 8 + g) * 2048;   // [parity][4][256]

    // init: h[-1]=0, tag=tagbase, parity 1, own 64 slots (4 b x 16 j)
    const int b0 = tid >> 4, jl0 = tid & 15;      // epilogue roles (tid<64)
    if (tid < 64) {
        __hip_atomic_store(&hb[1024 + b0 * 256 + s * 16 + jl0],
                           (unsigned long long)tagbase << 32,
                           __ATOMIC_RELAXED, __HIP_MEMORY_SCOPE_AGENT);
    }

    // xg: this thread adds xg(b = g*4 + kq, n_my) into batch-kq's partial
    const int b_x = g * 4 + kq;
    const __half* __restrict__ xgp =
        xg + ((size_t)(d * BATCH + b_x)) * T_LEN * G4 + n_my;

    const int i0 = tid * 4;              // this thread's 4 exchange slots
    float c_state = 0.f;                 // tid<64: cell of (b0, s*16+jl0)

    for (int st = 0; st < T_LEN; ++st) {
        const int t = d ? (T_LEN - 1 - st) : st;

        // prefetch xg (independent of h) before polling
        float xv = __half2float(xgp[(size_t)t * G4]);

        // poll own 4 tagged slots of parity (st+1)&1 for tag tagbase+st
        {
            const unsigned int exp = tagbase + (unsigned)st;
            unsigned long long* hsrc = hb + (size_t)((st + 1) & 1) * 1024;
            unsigned long long v0 = __hip_atomic_load(&hsrc[i0],     __ATOMIC_RELAXED, __HIP_MEMORY_SCOPE_AGENT);
            unsigned long long v1 = __hip_atomic_load(&hsrc[i0 + 1], __ATOMIC_RELAXED, __HIP_MEMORY_SCOPE_AGENT);
            unsigned long long v2 = __hip_atomic_load(&hsrc[i0 + 2], __ATOMIC_RELAXED, __HIP_MEMORY_SCOPE_AGENT);
            unsigned long long v3 = __hip_atomic_load(&hsrc[i0 + 3], __ATOMIC_RELAXED, __HIP_MEMORY_SCOPE_AGENT);
            while ((unsigned int)(v0 >> 32) != exp)
                v0 = __hip_atomic_load(&hsrc[i0],     __ATOMIC_RELAXED, __HIP_MEMORY_SCOPE_AGENT);
            while ((unsigned int)(v1 >> 32) != exp)
                v1 = __hip_atomic_load(&hsrc[i0 + 1], __ATOMIC_RELAXED, __HIP_MEMORY_SCOPE_AGENT);
            while ((unsigned int)(v2 >> 32) != exp)
                v2 = __hip_atomic_load(&hsrc[i0 + 2], __ATOMIC_RELAXED, __HIP_MEMORY_SCOPE_AGENT);
            while ((unsigned int)(v3 >> 32) != exp)
                v3 = __hip_atomic_load(&hsrc[i0 + 3], __ATOMIC_RELAXED, __HIP_MEMORY_SCOPE_AGENT);
            // slots i0..i0+3 = batch (tid>>6), j = (tid&63)*4 .. +3
            const int sb = tid >> 6, sg = tid & 63;
            hl2[sb * 128 + sg * 2] =
                pack_f16x2(__uint_as_float((unsigned)v0), __uint_as_float((unsigned)v1));
            hl2[sb * 128 + sg * 2 + 1] =
                pack_f16x2(__uint_as_float((unsigned)v2), __uint_as_float((unsigned)v3));
        }
        __syncthreads();   // hl2 ready (also orders prev-step scr reads vs writes)

        // 4 batches x 64-k dot products via fdot2; W in 32 VGPRs; h broadcast reads
        float a0 = (kq == 0) ? xv : 0.f;
        float a1 = (kq == 1) ? xv : 0.f;
        float a2 = (kq == 2) ? xv : 0.f;
        float a3 = (kq == 3) ? xv : 0.f;
        {
            const f16x2* hp = hl2 + kq * 32;
            #pragma unroll
            for (int k4 = 0; k4 < 8; ++k4) {
                float4 q0 = *reinterpret_cast<const float4*>(hp +   0 + k4 * 4);
                float4 q1 = *reinterpret_cast<const float4*>(hp + 128 + k4 * 4);
                float4 q2 = *reinterpret_cast<const float4*>(hp + 256 + k4 * 4);
                float4 q3 = *reinterpret_cast<const float4*>(hp + 384 + k4 * 4);
                f16x2 w0 = __builtin_bit_cast(f16x2, wh[k4 * 4 + 0]);
                f16x2 w1 = __builtin_bit_cast(f16x2, wh[k4 * 4 + 1]);
                f16x2 w2 = __builtin_bit_cast(f16x2, wh[k4 * 4 + 2]);
                f16x2 w3 = __builtin_bit_cast(f16x2, wh[k4 * 4 + 3]);
                a0 = dot2acc(__builtin_bit_cast(f16x2, q0.x), w0, a0);
                a0 = dot2acc(__builtin_bit_cast(f16x2, q0.y), w1, a0);
                a0 = dot2acc(__builtin_bit_cast(f16x2, q0.z), w2, a0);
                a0 = dot2acc(__builtin_bit_cast(f16x2, q0.w), w3, a0);
                a1 = dot2acc(__builtin_bit_cast(f16x2, q1.x), w0, a1);
                a1 = dot2acc(__builtin_bit_cast(f16x2, q1.y), w1, a1);
                a1 = dot2acc(__builtin_bit_cast(f16x2, q1.z), w2, a1);
                a1 = dot2acc(__builtin_bit_cast(f16x2, q1.w), w3, a1);
                a2 = dot2acc(__builtin_bit_cast(f16x2, q2.x), w0, a2);
                a2 = dot2acc(__builtin_bit_cast(f16x2, q2.y), w1, a2);
                a2 = dot2acc(__builtin_bit_cast(f16x2, q2.z), w2, a2);
                a2 = dot2acc(__builtin_bit_cast(f16x2, q2.w), w3, a2);
                a3 = dot2acc(__builtin_bit_cast(f16x2, q3.x), w0, a3);
                a3 = dot2acc(__builtin_bit_cast(f16x2, q3.y), w1, a3);
                a3 = dot2acc(__builtin_bit_cast(f16x2, q3.z), w2, a3);
                a3 = dot2acc(__builtin_bit_cast(f16x2, q3.w), w3, a3);
            }
        }
        scr[kq * 256 +   0 + col] = a0;
        scr[kq * 256 +  64 + col] = a1;
        scr[kq * 256 + 128 + col] = a2;
        scr[kq * 256 + 192 + col] = a3;
        __syncthreads();

        if (tid < 64) {
            float gi = scr[b0 * 64 +       jl0] + scr[256 + b0 * 64 +       jl0]
                     + scr[512 + b0 * 64 +       jl0] + scr[768 + b0 * 64 +       jl0];
            float gf = scr[b0 * 64 +  16 + jl0] + scr[256 + b0 * 64 +  16 + jl0]
                     + scr[512 + b0 * 64 +  16 + jl0] + scr[768 + b0 * 64 +  16 + jl0];
            float gg = scr[b0 * 64 +  32 + jl0] + scr[256 + b0 * 64 +  32 + jl0]
                     + scr[512 + b0 * 64 +  32 + jl0] + scr[768 + b0 * 64 +  32 + jl0];
            float go = scr[b0 * 64 +  48 + jl0] + scr[256 + b0 * 64 +  48 + jl0]
                     + scr[512 + b0 * 64 +  48 + jl0] + scr[768 + b0 * 64 +  48 + jl0];
            float ii = sigm(gi);
            float ff = sigm(gf);
            float g2 = tanh_fast(gg);
            float oo = sigm(go);
            c_state = ff * c_state + ii * g2;
            float h = oo * tanh_fast(c_state);
            int j = s * 16 + jl0;
            unsigned long long pv =
                ((unsigned long long)(tagbase + (unsigned)st + 1u) << 32) | __float_as_uint(h);
            __hip_atomic_store(&hb[(size_t)(st & 1) * 1024 + b0 * 256 + j], pv,
                               __ATOMIC_RELAXED, __HIP_MEMORY_SCOPE_AGENT);
            int b = g * 4 + b0;
            outp[((size_t)b * T_LEN + t) * (2 * HID) + d * HID + j] = h;
        }
        // next step's post-hl2-write barrier orders scr reuse; hl2 slots are
        // per-thread-exclusive so early hl2 writes of step st+1 are safe.
    }
}

extern "C" void kernel_launch(void* const* d_in, const int* in_sizes, int n_in,
                              void* d_out, int out_size, void* d_ws, size_t ws_size,
                              hipStream_t stream)
{
    const float* x       = (const float*)d_in[0];
    const float* W_ih_f0 = (const float*)d_in[1];
    const float* W_hh_f0 = (const float*)d_in[2];
    const float* b_ih_f0 = (const float*)d_in[3];
    const float* b_hh_f0 = (const float*)d_in[4];
    const float* W_ih_r0 = (const float*)d_in[5];
    const float* W_hh_r0 = (const float*)d_in[6];
    const float* b_ih_r0 = (const float*)d_in[7];
    const float* b_hh_r0 = (const float*)d_in[8];
    const float* W_ih_f1 = (const float*)d_in[9];
    const float* W_hh_f1 = (const float*)d_in[10];
    const float* b_ih_f1 = (const float*)d_in[11];
    const float* b_hh_f1 = (const float*)d_in[12];
    const float* W_ih_r1 = (const float*)d_in[13];
    const float* W_hh_r1 = (const float*)d_in[14];
    const float* b_ih_r1 = (const float*)d_in[15];
    const float* b_hh_r1 = (const float*)d_in[16];

    float* outp = (float*)d_out;

    __half* xg = (__half*)d_ws;
    const size_t xg_bytes = (size_t)2 * BATCH * T_LEN * G4 * sizeof(__half); // 134,217,728
    unsigned long long* hbt = (unsigned long long*)((char*)d_ws + xg_bytes); // 262,144 B

    // clean tag space every launch (no stale-tag pre-match, fully replay-safe)
    hipMemsetAsync(hbt, 0, 262144, stream);

    // ---- layer 0 ----
    proj_kernel<<<dim3(8, 256, 2), 256, 0, stream>>>(x, 256, W_ih_f0, W_ih_r0,
        b_ih_f0, b_hh_f0, b_ih_r0, b_hh_r0, xg);
    {
        const __half* xg_c = xg;
        unsigned int base0 = 1u;
        void* args[] = {(void*)&xg_c, (void*)&W_hh_f0, (void*)&W_hh_r0,
                        (void*)&outp, (void*)&hbt, (void*)&base0};
        hipLaunchCooperativeKernel(reinterpret_cast<const void*>(recur7_kernel),
                                   dim3(256), dim3(256), args, 0, stream);
    }

    // ---- layer 1 ----
    proj_kernel<<<dim3(8, 256, 2), 256, 0, stream>>>(outp, 512, W_ih_f1, W_ih_r1,
        b_ih_f1, b_hh_f1, b_ih_r1, b_hh_r1, xg);
    {
        const __half* xg_c = xg;
        unsigned int base1 = 4096u;
        void* args[] = {(void*)&xg_c, (void*)&W_hh_f1, (void*)&W_hh_r1,
                        (void*)&outp, (void*)&hbt, (void*)&base1};
        hipLaunchCooperativeKernel(reinterpret_cast<const void*>(recur7_kernel),
                                   dim3(256), dim3(256), args, 0, stream);
    }
}